// Round 2
// baseline (484.940 us; speedup 1.0000x reference)
//
#include <hip/hip_runtime.h>

typedef __attribute__((ext_vector_type(8))) short bf16x8;
typedef __attribute__((ext_vector_type(4))) float f32x4;

__device__ __forceinline__ unsigned short f2bf(float f) {
    union { float f; unsigned u; } v; v.f = f;
    unsigned r = (v.u + 0x7FFFu + ((v.u >> 16) & 1u)) >> 16;   // round-to-nearest-even
    return (unsigned short)r;
}

// ---------------- K0: mean-pool over T=4 + bf16 cast, padded [Mpad][320] ----------------
__global__ void pool_kernel(const float* __restrict__ x, unsigned short* __restrict__ xm,
                            int N, int Mpad) {
    int tid = blockIdx.x * 256 + threadIdx.x;
    if (tid >= Mpad * 40) return;
    int n = tid / 40, k8 = tid % 40;
    int k = k8 * 8;
    float v[8] = {0.f,0.f,0.f,0.f,0.f,0.f,0.f,0.f};
    if (n < N && k < 300) {
        const float* xp = x + (size_t)n * 1200 + k;
        #pragma unroll
        for (int t = 0; t < 4; ++t) {
            const float4 lo = *(const float4*)(xp + t * 300);
            v[0] += lo.x; v[1] += lo.y; v[2] += lo.z; v[3] += lo.w;
            if (k + 4 < 300) {   // k==296 tail: cols 300..303 stay zero
                const float4 hi = *(const float4*)(xp + t * 300 + 4);
                v[4] += hi.x; v[5] += hi.y; v[6] += hi.z; v[7] += hi.w;
            }
        }
    }
    union { unsigned short u[8]; bf16x8 vec; } p;
    #pragma unroll
    for (int j = 0; j < 8; ++j) p.u[j] = f2bf(v[j] * 0.25f);
    *(bf16x8*)(xm + (size_t)tid * 8) = p.vec;   // tid*8 == n*320 + k
}

// ---------------- zero counters ----------------
__global__ void zero3_kernel(int* deg, int* cnt, int* cur, int N) {
    int i = blockIdx.x * 256 + threadIdx.x;
    if (i < N) { deg[i] = 0; cnt[i] = 0; cur[i] = 0; }
}

// ---------------- degree (on row/source) + in-degree counts (on col/dest) ----------------
__global__ void degcnt_kernel(const int* __restrict__ ei, int E,
                              int* __restrict__ deg, int* __restrict__ cnt) {
    int e = blockIdx.x * 256 + threadIdx.x;
    if (e >= E) return;
    atomicAdd(&deg[ei[e]], 1);        // row
    atomicAdd(&cnt[ei[E + e]], 1);    // col
}

__global__ void dis_kernel(const int* __restrict__ deg, float* __restrict__ dis, int N) {
    int i = blockIdx.x * 256 + threadIdx.x;
    if (i < N) dis[i] = 1.0f / sqrtf((float)(deg[i] + 1));   // +1 self-loop
}

// ---------------- single-block exclusive scan: cnt -> indptr ----------------
__global__ void scan_kernel(const int* __restrict__ cnt, int* __restrict__ indptr, int n) {
    const int T = 1024;
    __shared__ int sm[T];
    int chunk = (n + T - 1) / T;
    int lo = threadIdx.x * chunk;
    int hi = lo + chunk; if (hi > n) hi = n;
    int s = 0;
    for (int i = lo; i < hi; ++i) s += cnt[i];
    sm[threadIdx.x] = s;
    __syncthreads();
    for (int off = 1; off < T; off <<= 1) {
        int t = (threadIdx.x >= (unsigned)off) ? sm[threadIdx.x - off] : 0;
        __syncthreads();
        sm[threadIdx.x] += t;
        __syncthreads();
    }
    int excl = (threadIdx.x == 0) ? 0 : sm[threadIdx.x - 1];
    for (int i = lo; i < hi; ++i) { indptr[i] = excl; excl += cnt[i]; }
    if (threadIdx.x == T - 1) indptr[n] = excl;   // == E
}

// ---------------- CSR fill: csr[indptr[col]+slot] = row ----------------
__global__ void fill_kernel(const int* __restrict__ ei, int E,
                            const int* __restrict__ indptr, int* __restrict__ cur,
                            int* __restrict__ csr) {
    int e = blockIdx.x * 256 + threadIdx.x;
    if (e >= E) return;
    int r = ei[e], c = ei[E + e];
    int pos = indptr[c] + atomicAdd(&cur[c], 1);
    csr[pos] = r;
}

// ---------------- weight prep: W[300][300] f32 -> Wp[304][320] bf16 (zero pad) ----------------
__global__ void wprep_kernel(const float* __restrict__ W1, const float* __restrict__ b1,
                             const float* __restrict__ W2, const float* __restrict__ b2,
                             unsigned short* __restrict__ Wp1, unsigned short* __restrict__ Wp2,
                             float* __restrict__ bp1, float* __restrict__ bp2) {
    int tid = blockIdx.x * 256 + threadIdx.x;
    if (tid >= 304 * 320) return;
    int o = tid / 320, k = tid % 320;
    bool in = (o < 300) && (k < 300);
    Wp1[tid] = f2bf(in ? W1[o * 300 + k] : 0.f);
    Wp2[tid] = f2bf(in ? W2[o * 300 + k] : 0.f);
    if (tid < 304) { bp1[tid] = tid < 300 ? b1[tid] : 0.f; bp2[tid] = tid < 300 ? b2[tid] : 0.f; }
}

// ---------------- GEMM: g[n][o] = dis[n]*(sum_k A[n][k]*Wp[o][k] + bp[o]) ----------------
// A: [Mpad][320] bf16, Wp: [304][320] bf16. Block = 4 waves, wave owns 32 rows, BM=128.
// mfma_f32_16x16x32_bf16 fragments: A lane l: row=l&15, k=(l>>4)*8+j (8 contiguous bf16);
// B lane l: col=l&15, same k; D lane l: col=l&15, row=(l>>4)*4+r  [measured m89/m91].
__global__ __launch_bounds__(256) void gemm_kernel(
    const unsigned short* __restrict__ A, const unsigned short* __restrict__ Wp,
    const float* __restrict__ bp, const float* __restrict__ dis,
    float* __restrict__ g, int N)
{
    const int lane = threadIdx.x & 63;
    const int wave = threadIdx.x >> 6;
    const int l15 = lane & 15, lhi = lane >> 4;
    const int rowBase = blockIdx.x * 128 + wave * 32;

    f32x4 acc0[19], acc1[19];
    #pragma unroll
    for (int i = 0; i < 19; ++i) { acc0[i] = (f32x4){0.f,0.f,0.f,0.f}; acc1[i] = (f32x4){0.f,0.f,0.f,0.f}; }

    const unsigned short* Ap0 = A + (size_t)(rowBase + l15) * 320 + lhi * 8;
    const unsigned short* Ap1 = Ap0 + 16 * 320;
    const unsigned short* Wl  = Wp + (size_t)l15 * 320 + lhi * 8;

    for (int ks = 0; ks < 10; ++ks) {
        bf16x8 a0 = *(const bf16x8*)(Ap0 + ks * 32);
        bf16x8 a1 = *(const bf16x8*)(Ap1 + ks * 32);
        #pragma unroll
        for (int cf = 0; cf < 19; ++cf) {
            bf16x8 b = *(const bf16x8*)(Wl + cf * 16 * 320 + ks * 32);
            acc0[cf] = __builtin_amdgcn_mfma_f32_16x16x32_bf16(a0, b, acc0[cf], 0, 0, 0);
            acc1[cf] = __builtin_amdgcn_mfma_f32_16x16x32_bf16(a1, b, acc1[cf], 0, 0, 0);
        }
    }

    const int n0 = rowBase + lhi * 4;
    float d0[4], d1[4];
    #pragma unroll
    for (int r = 0; r < 4; ++r) {
        d0[r] = (n0 + r      < N) ? dis[n0 + r]      : 0.f;
        d1[r] = (n0 + 16 + r < N) ? dis[n0 + 16 + r] : 0.f;
    }
    #pragma unroll
    for (int cf = 0; cf < 19; ++cf) {
        int o = cf * 16 + l15;
        if (o < 300) {
            float bo = bp[o];
            #pragma unroll
            for (int r = 0; r < 4; ++r) {
                if (n0 + r < N)      g[(size_t)(n0 + r) * 300 + o]      = d0[r] * (acc0[cf][r] + bo);
                if (n0 + 16 + r < N) g[(size_t)(n0 + 16 + r) * 300 + o] = d1[r] * (acc1[cf][r] + bo);
            }
        }
    }
}

// ---------------- propagate ----------------
// g is PRE-SCALED: g[n] = dis[n]*h[n]. Message for edge (src->n) is exactly g[src];
// self-loop message is g[n]. out[i] = dis[i] * (g[i] + sum_{e:col=i} g[src]).
// (Round-1 bug: we multiplied by dis again inside the sum -> dis^2 per message.)
// MODE 0: write f32 to out (final). MODE 1: leaky_relu + bf16-cast, write padded [Mpad][320].
template<int MODE>
__global__ void prop_kernel(const float* __restrict__ g, const int* __restrict__ indptr,
                            const int* __restrict__ csr, const float* __restrict__ dis,
                            void* __restrict__ outp, int N, int Mpad) {
    int wave = threadIdx.x >> 6;
    int lane = threadIdx.x & 63;
    int n = blockIdx.x * 4 + wave;
    if (n >= (MODE ? Mpad : N)) return;
    float acc[5] = {0.f,0.f,0.f,0.f,0.f};
    if (n < N) {
        const float* gn = g + (size_t)n * 300;
        #pragma unroll
        for (int s = 0; s < 5; ++s) { int f = lane + 64 * s; if (f < 300) acc[s] = gn[f]; }
        int beg = indptr[n], end = indptr[n + 1];
        for (int j = beg; j < end; ++j) {
            int src = csr[j];
            const float* gs = g + (size_t)src * 300;
            #pragma unroll
            for (int s = 0; s < 5; ++s) { int f = lane + 64 * s; if (f < 300) acc[s] += gs[f]; }
        }
        float dn = dis[n];
        #pragma unroll
        for (int s = 0; s < 5; ++s) acc[s] *= dn;
    }
    if (MODE == 0) {
        float* out = (float*)outp + (size_t)n * 300;
        #pragma unroll
        for (int s = 0; s < 5; ++s) { int f = lane + 64 * s; if (f < 300) out[f] = acc[s]; }
    } else {
        unsigned short* h = (unsigned short*)outp + (size_t)n * 320;
        #pragma unroll
        for (int s = 0; s < 5; ++s) {
            int f = lane + 64 * s;
            if (f < 300) {
                float v = acc[s];
                v = v > 0.f ? v : 0.01f * v;      // leaky_relu(0.01)
                h[f] = f2bf(v);
            } else if (f < 320) {
                h[f] = 0;                          // K-pad for GEMM2
            }
        }
    }
}

extern "C" void kernel_launch(void* const* d_in, const int* in_sizes, int n_in,
                              void* d_out, int out_size, void* d_ws, size_t ws_size,
                              hipStream_t stream) {
    const float* x  = (const float*)d_in[0];
    const int*   ei = (const int*)d_in[1];
    const float* W1 = (const float*)d_in[2];
    const float* b1 = (const float*)d_in[3];
    const float* W2 = (const float*)d_in[4];
    const float* b2 = (const float*)d_in[5];
    float* out = (float*)d_out;

    const int N = in_sizes[0] / 1200;     // 50000
    const int E = in_sizes[1] / 2;        // 250000
    const int Mpad = ((N + 127) / 128) * 128;   // 50048

    // ---- carve workspace (256B aligned) ----
    char* p = (char*)d_ws;
    auto carve = [&](size_t bytes) -> char* {
        char* r = p; p += (bytes + 255) & ~(size_t)255; return r;
    };
    unsigned short* xm   = (unsigned short*)carve((size_t)Mpad * 320 * 2);  // 32 MB
    unsigned short* hb   = (unsigned short*)carve((size_t)Mpad * 320 * 2);  // 32 MB
    float* g2            = (float*)carve((size_t)N * 300 * 4);              // 60 MB
    float* dis           = (float*)carve((size_t)N * 4);
    int* deg             = (int*)carve((size_t)N * 4);
    int* cnt             = (int*)carve((size_t)N * 4);
    int* indptr          = (int*)carve((size_t)(N + 1) * 4);
    int* cur             = (int*)carve((size_t)N * 4);
    int* csr             = (int*)carve((size_t)E * 4);
    unsigned short* Wp1  = (unsigned short*)carve(304 * 320 * 2);
    unsigned short* Wp2  = (unsigned short*)carve(304 * 320 * 2);
    float* bp1           = (float*)carve(304 * 4);
    float* bp2           = (float*)carve(304 * 4);

    zero3_kernel <<<(N + 255) / 256, 256, 0, stream>>>(deg, cnt, cur, N);
    pool_kernel  <<<(Mpad * 40 + 255) / 256, 256, 0, stream>>>(x, xm, N, Mpad);
    degcnt_kernel<<<(E + 255) / 256, 256, 0, stream>>>(ei, E, deg, cnt);
    dis_kernel   <<<(N + 255) / 256, 256, 0, stream>>>(deg, dis, N);
    scan_kernel  <<<1, 1024, 0, stream>>>(cnt, indptr, N);
    fill_kernel  <<<(E + 255) / 256, 256, 0, stream>>>(ei, E, indptr, cur, csr);
    wprep_kernel <<<(304 * 320 + 255) / 256, 256, 0, stream>>>(W1, b1, W2, b2, Wp1, Wp2, bp1, bp2);

    // layer 1: g1 = dis*(xm@W1^T + b1) -> stored in d_out (scratch), then prop+leaky -> hb (bf16)
    gemm_kernel  <<<Mpad / 128, 256, 0, stream>>>(xm, Wp1, bp1, dis, out, N);
    prop_kernel<1><<<Mpad / 4, 256, 0, stream>>>(out, indptr, csr, dis, hb, N, Mpad);
    // layer 2: g2 = dis*(h@W2^T + b2), then final prop -> d_out
    gemm_kernel  <<<Mpad / 128, 256, 0, stream>>>(hb, Wp2, bp2, dis, g2, N);
    prop_kernel<0><<<(N + 3) / 4, 256, 0, stream>>>(g2, indptr, csr, dis, out, N, Mpad);
}